// Round 4
// baseline (107.944 us; speedup 1.0000x reference)
//
#include <hip/hip_runtime.h>

// Self-attention (SAGAN-style): B=8, C=64, H=W=64 -> N=4096, E=C/8=8.
// Round 15: amortize K/V return 2x more. r14 confirmed attn is VMEM-return
// bound (dedup'd K gained 2.3us). Same mechanism, next level: 4 q-tiles per
// block (64 queries, grid 512 = 2 blocks/CU). The same 3 loads/chunk (kf +
// 2 V panels) now feed 4 tiles: per-CU return ~5us -> ~2.5us, L2 traffic
// 196 -> 98MB. Total MFMA/exp work invariant (N^2), so VALU (~4.5us floor:
// 134M fexp2 pairs + packs) becomes the clean bound. Cost: 16 masked Q
// frags (4 tiles x 4 groups) = 64 VGPR -> launch_bounds(256,2) [the old
// ,4 would cap at 128 VGPR and spill]. 2 waves/SIMD is enough: depth-2
// prefetch covers ~700cyc/chunk, MFMA+VALU co-issue across 8 waves/CU.
// S map key = 16g + 4*quad + r, pack->PV permuted key map, ones-row
// denominator all verified r6-r14 and unchanged; VL stride 13 (was 12)
// kills the epilogue 8-way bank conflict. Predicted total ~103-105us.
// Kept: r13 3-pass qkv (known-good), fexp2 Schraudolph (absmax 0.0098),
// panel V [b][128][16][32] with ones-row 8, full-wave dedup'd K loads,
// depth-2 register prefetch, v_perm pack, fused Wo/residual epilogue,
// split-K 4 waves + LDS combine.
// Non-attn ~84us is fixed harness overhead (0xAA re-poison fills at ~80%
// of HBM peak); the two kernels are the only lever (~23us budget).

#define BB   8
#define CC   64
#define NPIX 4096
#define EE   8
#define BN   (BB*NPIX)        // 32768
#define YSZ  (BB*CC*NPIX)     // 2097152
#define LOG2E 1.4426950408889634f

typedef __attribute__((ext_vector_type(8))) short bf16x8;
typedef __attribute__((ext_vector_type(4))) float f32x4;

__device__ __forceinline__ unsigned short f2bf_rne(float x) {
    unsigned u = __float_as_uint(x);
    u += 0x7FFFu + ((u >> 16) & 1u);
    return (unsigned short)(u >> 16);
}
// dst = [hi16(a), hi16(b)] in one v_perm_b32 (truncation; bias cancels in
// the softmax normalize since l sums the same truncated p via the ones-row).
__device__ __forceinline__ unsigned pack_bf_trunc(float a, float b) {
    return __builtin_amdgcn_perm(__float_as_uint(b), __float_as_uint(a),
                                 0x07060302u);
}
// Schraudolph exp2: piecewise-linear mantissa, error-centered magic.
// (127 - 0.0347) * 2^23 = 1065062131; max relative err ~ +-3.5%, zero-mean.
// 2 full-rate VALU ops vs quarter-rate v_exp_f32.
__device__ __forceinline__ float fexp2(float x) {
    return __int_as_float((int)fmaf(x, 8388608.f, 1065062131.f));
}

// ---- K1: QKV projection; V written in panel layout (r11/r13 3-pass) ----
__global__ __launch_bounds__(256) void qkv_kernel(
    const float* __restrict__ x,
    const float* __restrict__ Wk, const float* __restrict__ bk,
    const float* __restrict__ Wq, const float* __restrict__ bq,
    const float* __restrict__ Wv, const float* __restrict__ bv,
    unsigned short* __restrict__ QT, unsigned short* __restrict__ KT,
    unsigned short* __restrict__ VT)
{
    const int proj = blockIdx.y;  // 0=Q, 1=K, 2=V
    const float* W    = (proj == 0) ? Wq : (proj == 1) ? Wk : Wv;
    const float* bias = (proj == 0) ? bq : (proj == 1) ? bk : bv;

    const int bm = blockIdx.x*256 + threadIdx.x;
    const int b  = bm >> 12;
    const int n  = bm & (NPIX-1);
    const float* xb = x + (size_t)b*CC*NPIX + n;

    float xv[CC];
    #pragma unroll
    for (int c = 0; c < CC; ++c) xv[c] = xb[(size_t)c*NPIX];

    float f[EE];
    #pragma unroll
    for (int e = 0; e < EE; ++e) {
        float acc = bias[e];
        #pragma unroll
        for (int c = 0; c < CC; ++c) acc = fmaf(W[e*CC+c], xv[c], acc);
        f[e] = acc;
    }

    if (proj == 0) {
        union { unsigned short s[8]; uint4 v; } t;
        #pragma unroll
        for (int e = 0; e < EE; ++e) t.s[e] = f2bf_rne(f[e] * LOG2E);
        *(uint4*)(QT + (size_t)bm*EE) = t.v;
    } else if (proj == 1) {
        union { unsigned short s[8]; uint4 v; } t;
        #pragma unroll
        for (int e = 0; e < EE; ++e) t.s[e] = f2bf_rne(f[e]);
        *(uint4*)(KT + (size_t)bm*EE) = t.v;
    } else {
        // panel p = n>>5; within-row short offset for key c = n&31:
        // quad q(c) block of 8: [0..3]=keys 4q..4q+3, [4..7]=keys 16+4q..+3
        const int p   = n >> 5;
        const int c   = n & 31;
        const int off = ((c & 15) >> 2)*8 + ((c >> 4) << 2) + (c & 3);
        unsigned short* vp = VT + ((size_t)(b*128 + p)*16)*32 + off;
        #pragma unroll
        for (int e = 0; e < EE; ++e) vp[e*32] = f2bf_rne(f[e]);
        vp[8*32] = 0x3F80;                         // ones row -> l via GEMM2
    }
}

// ---- K2: flash attention, 64-key chunks x 4 q-tiles + fused epilogue ----
// Block = 64 queries; 4 waves split the 4096 keys x4. Grid = 8*64 = 512.
__global__ __launch_bounds__(256, 2) void attn_fused(
    const unsigned short* __restrict__ QT, const unsigned short* __restrict__ KT,
    const unsigned short* __restrict__ VT,
    const float* __restrict__ x, const float* __restrict__ Wo,
    const float* __restrict__ bo, const float* __restrict__ gamma,
    float* __restrict__ out)
{
    __shared__ float OB[3*4*256];  // waves 1..3 x tiles 0..3 x 64 lanes x f32x4
    __shared__ float VL[64*13];    // normalized v per pixel (stride 13: no conflicts)
    __shared__ float Wos[CC*9];    // stride 9: conflict-free epilogue reads
    __shared__ float bos[CC];

    const int tid  = threadIdx.x;
    const int wave = tid >> 6, lane = tid & 63;
    const int quad = lane >> 4, lm = lane & 15;
    const int b  = blockIdx.x >> 6;
    const int m0 = (blockIdx.x & 63) * 64;

    for (int i = tid; i < CC*EE; i += 256) Wos[(i>>3)*9 + (i&7)] = Wo[i];
    if (tid < CC) bos[tid] = bo[tid];

    // Q fragments per (tile t, key-group g): tile-t Q rows in quad-g lanes,
    // zeros elsewhere. mfma(kf, qf[t][g]) reads A only from quad-g lanes
    // (B zero in other k-slots) = keys 16g..16g+15 of the 64-key kf load.
    // S output reg map: key = 16g + 4*quad + r, query col = m0 + 16t + lm.
    const bf16x8 kz = {0,0,0,0,0,0,0,0};
    bf16x8 qf[4][4];
    #pragma unroll
    for (int t = 0; t < 4; ++t) {
        bf16x8 qt = *(const bf16x8*)(QT + (size_t)(b*NPIX + m0 + 16*t + lm)*EE);
        #pragma unroll
        for (int g = 0; g < 4; ++g) qf[t][g] = (quad == g) ? qt : kz;
    }

    f32x4 oacc[4];
    #pragma unroll
    for (int t = 0; t < 4; ++t) oacc[t] = (f32x4){0.f,0.f,0.f,0.f};
    const f32x4 zc = {0.f,0.f,0.f,0.f};

    const unsigned short* Kb = KT + (size_t)b*NPIX*EE;
    const int n_start = wave*1024;                 // split-K: 1024 keys/wave
    // Full-wave K load: lane l -> key n_start + l (1KB coalesced, 0 waste).
    const unsigned short* kl = Kb + (size_t)(n_start + lane)*EE;
    // V panel: row clamp (rows 9..15 -> 8; same lines, C rows 9..15 discarded)
    const int lmv = (lm < 9) ? lm : 8;
    const unsigned short* vl = VT + ((size_t)(b*128 + (n_start >> 5))*16 + lmv)*32
                                  + quad*8;

    // 2-deep register pipeline over 16 chunks of 64 keys
    bf16x8 kfa  = *(const bf16x8*)(kl);
    bf16x8 vf0a = *(const bf16x8*)(vl);
    bf16x8 vf1a = *(const bf16x8*)(vl + 512);
    bf16x8 kfb  = *(const bf16x8*)(kl + 64*EE);
    bf16x8 vf0b = *(const bf16x8*)(vl + 1024);
    bf16x8 vf1b = *(const bf16x8*)(vl + 1536);
    kl += 128*EE; vl += 2048;

    for (int ch = 0; ch < 16; ++ch) {
        bf16x8 kf = kfa, vf0 = vf0a, vf1 = vf1a;
        kfa = kfb; vf0a = vf0b; vf1a = vf1b;       // ping-pong, no movs
        if (ch < 14) {                             // prefetch chunk ch+2
            kfb  = *(const bf16x8*)(kl);
            vf0b = *(const bf16x8*)(vl);
            vf1b = *(const bf16x8*)(vl + 512);
            kl += 64*EE; vl += 1024;
        }

        #pragma unroll
        for (int t = 0; t < 4; ++t) {
            // s_g reg r = S[key 16g + 4*quad + r][query m0 + 16t + lm]
            f32x4 s0 = __builtin_amdgcn_mfma_f32_16x16x32_bf16(kf, qf[t][0], zc, 0, 0, 0);
            f32x4 s1 = __builtin_amdgcn_mfma_f32_16x16x32_bf16(kf, qf[t][1], zc, 0, 0, 0);
            f32x4 s2 = __builtin_amdgcn_mfma_f32_16x16x32_bf16(kf, qf[t][2], zc, 0, 0, 0);
            f32x4 s3 = __builtin_amdgcn_mfma_f32_16x16x32_bf16(kf, qf[t][3], zc, 0, 0, 0);

            float a0 = fexp2(s0.x), a1 = fexp2(s0.y);
            float a2 = fexp2(s0.z), a3 = fexp2(s0.w);
            float a4 = fexp2(s1.x), a5 = fexp2(s1.y);
            float a6 = fexp2(s1.z), a7 = fexp2(s1.w);
            float c0 = fexp2(s2.x), c1 = fexp2(s2.y);
            float c2 = fexp2(s2.z), c3 = fexp2(s2.w);
            float c4 = fexp2(s3.x), c5 = fexp2(s3.y);
            float c6 = fexp2(s3.z), c7 = fexp2(s3.w);

            // B2 fragment IS the C-layout regs under the permuted key map
            // (slot k=quad*8+j -> key quad*4+j (j<4) / 16+quad*4+(j-4)),
            // matching the V panel row layout. Verified r6-r14.
            union { unsigned u[4]; bf16x8 v; } p0, p1;
            p0.u[0] = pack_bf_trunc(a0, a1); p0.u[1] = pack_bf_trunc(a2, a3);
            p0.u[2] = pack_bf_trunc(a4, a5); p0.u[3] = pack_bf_trunc(a6, a7);
            p1.u[0] = pack_bf_trunc(c0, c1); p1.u[1] = pack_bf_trunc(c2, c3);
            p1.u[2] = pack_bf_trunc(c4, c5); p1.u[3] = pack_bf_trunc(c6, c7);
            oacc[t] = __builtin_amdgcn_mfma_f32_16x16x32_bf16(vf0, p0.v, oacc[t], 0, 0, 0);
            oacc[t] = __builtin_amdgcn_mfma_f32_16x16x32_bf16(vf1, p1.v, oacc[t], 0, 0, 0);
        }
    }

    // cross-wave combine; l rides along in C-row 8 (quad2 lanes, reg .x)
    if (wave != 0) {
        #pragma unroll
        for (int t = 0; t < 4; ++t)
            *(f32x4*)(OB + ((size_t)(wave-1)*4 + t)*256 + lane*4) = oacc[t];
    }
    __syncthreads();
    if (wave == 0) {
        #pragma unroll
        for (int t = 0; t < 4; ++t) {
            f32x4 oT = oacc[t];
            #pragma unroll
            for (int w = 0; w < 3; ++w)
                oT += *(f32x4*)(OB + ((size_t)w*4 + t)*256 + lane*4);
            float lT  = __shfl(oT.x, 32 + lm);     // row 8 = sum of trunc(p)
            float inv = 1.f / lT;
            if (quad < 2) {                        // rows e = quad*4+reg in 0..7
                f32x4 sT = { oT.x*inv, oT.y*inv, oT.z*inv, oT.w*inv };
                *(f32x4*)(VL + (16*t + lm)*13 + quad*4) = sT;
            }
        }
    }
    __syncthreads();

    // Fused epilogue: 64 px x 64 ch over 256 threads (16 ch each).
    const float g  = gamma[0];
    const int   px = tid & 63;
    const int   cg = tid >> 6;                     // 0..3
    const size_t base = (size_t)b*CC*NPIX + (m0 + px);
    float v[EE];
    #pragma unroll
    for (int e = 0; e < EE; ++e) v[e] = VL[px*13 + e];
    #pragma unroll
    for (int i = 0; i < 16; ++i) {
        const int c = cg*16 + i;
        float o = bos[c];
        #pragma unroll
        for (int e = 0; e < EE; ++e) o += Wos[c*9 + e] * v[e];
        out[(size_t)YSZ + base + (size_t)c*NPIX] = o;
        out[base + (size_t)c*NPIX] = g*o + x[base + (size_t)c*NPIX];
    }
    if (blockIdx.x == 0 && tid == 0) out[2*(size_t)YSZ] = g;  // gamma passthrough
}

extern "C" void kernel_launch(void* const* d_in, const int* in_sizes, int n_in,
                              void* d_out, int out_size, void* d_ws, size_t ws_size,
                              hipStream_t stream) {
    const float* x     = (const float*)d_in[0];
    const float* Wk    = (const float*)d_in[1];
    const float* bk    = (const float*)d_in[2];
    const float* Wq    = (const float*)d_in[3];
    const float* bq    = (const float*)d_in[4];
    const float* Wv    = (const float*)d_in[5];
    const float* bv    = (const float*)d_in[6];
    const float* Wo    = (const float*)d_in[7];
    const float* bo    = (const float*)d_in[8];
    const float* gamma = (const float*)d_in[9];
    float* out = (float*)d_out;

    // ws: QT(512KB) | KT(512KB) | VT(1MB bf16, panelized [b][128][16][32];
    // row 8 = ones, rows 9..15 poison -> only discarded C rows) = 2MB
    unsigned short* QT = (unsigned short*)d_ws;
    unsigned short* KT = QT + (size_t)BN*EE;
    unsigned short* VT = KT + (size_t)BN*EE;

    qkv_kernel<<<dim3(BN/256, 3), 256, 0, stream>>>(x, Wk, bk, Wq, bq, Wv, bv, QT, KT, VT);
    attn_fused<<<BB*64, 256, 0, stream>>>(QT, KT, VT, x, Wo, bo, gamma, out);
}

// Round 5
// 106.644 us; speedup vs baseline: 1.0122x; 1.0122x over previous
//
#include <hip/hip_runtime.h>

// Self-attention (SAGAN-style): B=8, C=64, H=W=64 -> N=4096, E=C/8=8.
// Round 16: attn REVERTED to exact r14 form (best measured: 107.3us
// component; r15's 4-tile amortization was neutral -> attn is no longer
// return-BW-bound after the K-dedup, and 1 wave/SIMD occupancy hurt).
// Single-variable change this round: qkv passes 3->1 over x in HBM terms.
// proj = WAVE id (block = 192 thr = 3 waves, same 64 pixels): waves 1,2
// re-read the same 16KB x-slice through L1/L2 -> HBM fetch 24MB -> 8MB,
// predicted qkv ~4.3 -> ~2us, total ~105us. Per-wave code is byte-identical
// to r13's per-block code; W/bias pointers forced to SGPR via readfirstlane
// (wave-uniformity of tid>>6 is not proven by the compiler; without it the
// 512 W reads/thread become vector loads). Grid 512 = 2 blocks/CU = 6
// waves/CU (r12's fused-qkv failure was 0.5 waves/SIMD; this keeps 1.5).
// Kept: fexp2 Schraudolph (absmax 0.0098, r13 A/B neutral-cost), panel V
// [b][128][16][32] with ones-row 8 (l = sum(p) on the MFMA pipe),
// in-register P via permuted key map (verified r6-r15), full-wave dedup'd
// K loads + 4 masked Q fragments (r14, confirmed -2.3us), 2 q-tiles/wave,
// depth-2 register prefetch, v_perm pack, fused Wo/residual epilogue,
// split-K 4 waves + LDS combine.
// Non-attn ~84us is fixed harness overhead (0xAA re-poison fills at ~80%
// of HBM peak); the two kernels are the only lever (~23us budget).

#define BB   8
#define CC   64
#define NPIX 4096
#define EE   8
#define BN   (BB*NPIX)        // 32768
#define YSZ  (BB*CC*NPIX)     // 2097152
#define LOG2E 1.4426950408889634f

typedef __attribute__((ext_vector_type(8))) short bf16x8;
typedef __attribute__((ext_vector_type(4))) float f32x4;

__device__ __forceinline__ unsigned short f2bf_rne(float x) {
    unsigned u = __float_as_uint(x);
    u += 0x7FFFu + ((u >> 16) & 1u);
    return (unsigned short)(u >> 16);
}
// dst = [hi16(a), hi16(b)] in one v_perm_b32 (truncation; bias cancels in
// the softmax normalize since l sums the same truncated p via the ones-row).
__device__ __forceinline__ unsigned pack_bf_trunc(float a, float b) {
    return __builtin_amdgcn_perm(__float_as_uint(b), __float_as_uint(a),
                                 0x07060302u);
}
// Schraudolph exp2: piecewise-linear mantissa, error-centered magic.
// (127 - 0.0347) * 2^23 = 1065062131; max relative err ~ +-3.5%, zero-mean.
// 2 full-rate VALU ops vs quarter-rate v_exp_f32.
__device__ __forceinline__ float fexp2(float x) {
    return __int_as_float((int)fmaf(x, 8388608.f, 1065062131.f));
}
// Force a (wave-uniform) pointer into SGPRs so dependent loads are s_loads.
__device__ __forceinline__ const float* rfl_ptr(const float* p) {
    unsigned long long u = (unsigned long long)p;
    unsigned lo = __builtin_amdgcn_readfirstlane((unsigned)u);
    unsigned hi = __builtin_amdgcn_readfirstlane((unsigned)(u >> 32));
    return (const float*)(((unsigned long long)hi << 32) | lo);
}

// ---- K1: QKV projection, proj = wave id; 3 waves share one x-slice ----
// Block = 192 thr = 3 waves over the SAME 64 pixels -> x fetched from HBM
// once, waves 1-2 hit L1/L2. Per-wave body identical to r13's per-block.
__global__ __launch_bounds__(192) void qkv_kernel(
    const float* __restrict__ x,
    const float* __restrict__ Wk, const float* __restrict__ bk,
    const float* __restrict__ Wq, const float* __restrict__ bq,
    const float* __restrict__ Wv, const float* __restrict__ bv,
    unsigned short* __restrict__ QT, unsigned short* __restrict__ KT,
    unsigned short* __restrict__ VT)
{
    const int proj = threadIdx.x >> 6;   // wave id: 0=Q, 1=K, 2=V
    const int lane = threadIdx.x & 63;
    const float* W    = rfl_ptr((proj == 0) ? Wq : (proj == 1) ? Wk : Wv);
    const float* bias = rfl_ptr((proj == 0) ? bq : (proj == 1) ? bk : bv);

    const int bm = blockIdx.x*64 + lane;
    const int b  = bm >> 12;
    const int n  = bm & (NPIX-1);
    const float* xb = x + (size_t)b*CC*NPIX + n;

    float xv[CC];
    #pragma unroll
    for (int c = 0; c < CC; ++c) xv[c] = xb[(size_t)c*NPIX];

    float f[EE];
    #pragma unroll
    for (int e = 0; e < EE; ++e) {
        float acc = bias[e];
        #pragma unroll
        for (int c = 0; c < CC; ++c) acc = fmaf(W[e*CC+c], xv[c], acc);
        f[e] = acc;
    }

    if (proj == 0) {
        union { unsigned short s[8]; uint4 v; } t;
        #pragma unroll
        for (int e = 0; e < EE; ++e) t.s[e] = f2bf_rne(f[e] * LOG2E);
        *(uint4*)(QT + (size_t)bm*EE) = t.v;
    } else if (proj == 1) {
        union { unsigned short s[8]; uint4 v; } t;
        #pragma unroll
        for (int e = 0; e < EE; ++e) t.s[e] = f2bf_rne(f[e]);
        *(uint4*)(KT + (size_t)bm*EE) = t.v;
    } else {
        // panel p = n>>5; within-row short offset for key c = n&31:
        // quad q(c) block of 8: [0..3]=keys 4q..4q+3, [4..7]=keys 16+4q..+3
        const int p   = n >> 5;
        const int c   = n & 31;
        const int off = ((c & 15) >> 2)*8 + ((c >> 4) << 2) + (c & 3);
        unsigned short* vp = VT + ((size_t)(b*128 + p)*16)*32 + off;
        #pragma unroll
        for (int e = 0; e < EE; ++e) vp[e*32] = f2bf_rne(f[e]);
        vp[8*32] = 0x3F80;                         // ones row -> l via GEMM2
    }
}

// ---- K2: flash attention, 64-key chunks, dedup'd K loads (r14 form) ----
// Block = 32 queries; 4 waves split the 4096 keys x4. Grid = 8*128 = 1024.
__global__ __launch_bounds__(256, 4) void attn_fused(
    const unsigned short* __restrict__ QT, const unsigned short* __restrict__ KT,
    const unsigned short* __restrict__ VT,
    const float* __restrict__ x, const float* __restrict__ Wo,
    const float* __restrict__ bo, const float* __restrict__ gamma,
    float* __restrict__ out)
{
    __shared__ float OB[3*2*256];  // waves 1..3 x {A,B} x 64 lanes x f32x4
    __shared__ float VL[32*12];    // normalized v per pixel
    __shared__ float Wos[CC*9];    // stride 9: conflict-free epilogue reads
    __shared__ float bos[CC];

    const int tid  = threadIdx.x;
    const int wave = tid >> 6, lane = tid & 63;
    const int quad = lane >> 4, lm = lane & 15;
    const int b  = blockIdx.x >> 7;
    const int m0 = (blockIdx.x & 127) * 32;

    for (int i = tid; i < CC*EE; i += 256) Wos[(i>>3)*9 + (i&7)] = Wo[i];
    if (tid < CC) bos[tid] = bo[tid];

    // Q fragments per key-group g: Q rows in quad-g lanes, zeros elsewhere.
    // Group-g S-MFMA mfma(kf, q[g]) reads A only from quad-g lanes (B zero
    // in other k-slots) = keys 16g..16g+15 of the 64-key kf load.
    const bf16x8 kz = {0,0,0,0,0,0,0,0};
    bf16x8 qtA = *(const bf16x8*)(QT + (size_t)(b*NPIX + m0 + lm)*EE);
    bf16x8 qtB = *(const bf16x8*)(QT + (size_t)(b*NPIX + m0 + 16 + lm)*EE);
    bf16x8 qA[4], qB[4];
    #pragma unroll
    for (int g = 0; g < 4; ++g) {
        qA[g] = (quad == g) ? qtA : kz;
        qB[g] = (quad == g) ? qtB : kz;
    }

    f32x4 oaccA = {0.f,0.f,0.f,0.f}, oaccB = {0.f,0.f,0.f,0.f};
    const f32x4 zc = {0.f,0.f,0.f,0.f};

    const unsigned short* Kb = KT + (size_t)b*NPIX*EE;
    const int n_start = wave*1024;                 // split-K: 1024 keys/wave
    // Full-wave K load: lane l -> key n_start + l (1KB coalesced, 0 waste).
    const unsigned short* kl = Kb + (size_t)(n_start + lane)*EE;
    // V panel: row clamp (rows 9..15 -> 8; same lines, C rows 9..15 discarded)
    const int lmv = (lm < 9) ? lm : 8;
    const unsigned short* vl = VT + ((size_t)(b*128 + (n_start >> 5))*16 + lmv)*32
                                  + quad*8;

    // 2-deep register pipeline over 16 chunks of 64 keys
    bf16x8 kfa  = *(const bf16x8*)(kl);
    bf16x8 vf0a = *(const bf16x8*)(vl);
    bf16x8 vf1a = *(const bf16x8*)(vl + 512);
    bf16x8 kfb  = *(const bf16x8*)(kl + 64*EE);
    bf16x8 vf0b = *(const bf16x8*)(vl + 1024);
    bf16x8 vf1b = *(const bf16x8*)(vl + 1536);
    kl += 128*EE; vl += 2048;

    #pragma unroll 2
    for (int ch = 0; ch < 16; ++ch) {
        bf16x8 kf = kfa, vf0 = vf0a, vf1 = vf1a;
        kfa = kfb; vf0a = vf0b; vf1a = vf1b;       // ping-pong, no movs
        if (ch < 14) {                             // prefetch chunk ch+2
            kfb  = *(const bf16x8*)(kl);
            vf0b = *(const bf16x8*)(vl);
            vf1b = *(const bf16x8*)(vl + 512);
            kl += 64*EE; vl += 1024;
        }

        // ---- tile A ----
        // s_g reg r = S[key 16g + 4*quad + r][query m0+lm]
        f32x4 s0a = __builtin_amdgcn_mfma_f32_16x16x32_bf16(kf, qA[0], zc, 0, 0, 0);
        f32x4 s1a = __builtin_amdgcn_mfma_f32_16x16x32_bf16(kf, qA[1], zc, 0, 0, 0);
        f32x4 s2a = __builtin_amdgcn_mfma_f32_16x16x32_bf16(kf, qA[2], zc, 0, 0, 0);
        f32x4 s3a = __builtin_amdgcn_mfma_f32_16x16x32_bf16(kf, qA[3], zc, 0, 0, 0);
        {
            float a0 = fexp2(s0a.x), a1 = fexp2(s0a.y);
            float a2 = fexp2(s0a.z), a3 = fexp2(s0a.w);
            float a4 = fexp2(s1a.x), a5 = fexp2(s1a.y);
            float a6 = fexp2(s1a.z), a7 = fexp2(s1a.w);
            float c0 = fexp2(s2a.x), c1 = fexp2(s2a.y);
            float c2 = fexp2(s2a.z), c3 = fexp2(s2a.w);
            float c4 = fexp2(s3a.x), c5 = fexp2(s3a.y);
            float c6 = fexp2(s3a.z), c7 = fexp2(s3a.w);
            // B2 fragment IS the C-layout regs under the permuted key map
            // (slot k=quad*8+j -> key quad*4+j (j<4) / 16+quad*4+(j-4)),
            // matching the V panel row layout. Verified r6-r15.
            union { unsigned u[4]; bf16x8 v; } p0, p1;
            p0.u[0] = pack_bf_trunc(a0, a1); p0.u[1] = pack_bf_trunc(a2, a3);
            p0.u[2] = pack_bf_trunc(a4, a5); p0.u[3] = pack_bf_trunc(a6, a7);
            p1.u[0] = pack_bf_trunc(c0, c1); p1.u[1] = pack_bf_trunc(c2, c3);
            p1.u[2] = pack_bf_trunc(c4, c5); p1.u[3] = pack_bf_trunc(c6, c7);
            oaccA = __builtin_amdgcn_mfma_f32_16x16x32_bf16(vf0, p0.v, oaccA, 0, 0, 0);
            oaccA = __builtin_amdgcn_mfma_f32_16x16x32_bf16(vf1, p1.v, oaccA, 0, 0, 0);
        }
        // ---- tile B ----
        f32x4 s0b = __builtin_amdgcn_mfma_f32_16x16x32_bf16(kf, qB[0], zc, 0, 0, 0);
        f32x4 s1b = __builtin_amdgcn_mfma_f32_16x16x32_bf16(kf, qB[1], zc, 0, 0, 0);
        f32x4 s2b = __builtin_amdgcn_mfma_f32_16x16x32_bf16(kf, qB[2], zc, 0, 0, 0);
        f32x4 s3b = __builtin_amdgcn_mfma_f32_16x16x32_bf16(kf, qB[3], zc, 0, 0, 0);
        {
            float a0 = fexp2(s0b.x), a1 = fexp2(s0b.y);
            float a2 = fexp2(s0b.z), a3 = fexp2(s0b.w);
            float a4 = fexp2(s1b.x), a5 = fexp2(s1b.y);
            float a6 = fexp2(s1b.z), a7 = fexp2(s1b.w);
            float c0 = fexp2(s2b.x), c1 = fexp2(s2b.y);
            float c2 = fexp2(s2b.z), c3 = fexp2(s2b.w);
            float c4 = fexp2(s3b.x), c5 = fexp2(s3b.y);
            float c6 = fexp2(s3b.z), c7 = fexp2(s3b.w);
            union { unsigned u[4]; bf16x8 v; } p0, p1;
            p0.u[0] = pack_bf_trunc(a0, a1); p0.u[1] = pack_bf_trunc(a2, a3);
            p0.u[2] = pack_bf_trunc(a4, a5); p0.u[3] = pack_bf_trunc(a6, a7);
            p1.u[0] = pack_bf_trunc(c0, c1); p1.u[1] = pack_bf_trunc(c2, c3);
            p1.u[2] = pack_bf_trunc(c4, c5); p1.u[3] = pack_bf_trunc(c6, c7);
            oaccB = __builtin_amdgcn_mfma_f32_16x16x32_bf16(vf0, p0.v, oaccB, 0, 0, 0);
            oaccB = __builtin_amdgcn_mfma_f32_16x16x32_bf16(vf1, p1.v, oaccB, 0, 0, 0);
        }
    }

    // cross-wave combine; l rides along in C-row 8 (quad2 lanes, reg .x)
    if (wave != 0) {
        *(f32x4*)(OB + ((size_t)(wave-1)*2 + 0)*256 + lane*4) = oaccA;
        *(f32x4*)(OB + ((size_t)(wave-1)*2 + 1)*256 + lane*4) = oaccB;
    }
    __syncthreads();
    if (wave == 0) {
        f32x4 oA = oaccA, oB = oaccB;
        #pragma unroll
        for (int w = 0; w < 3; ++w) {
            oA += *(f32x4*)(OB + ((size_t)w*2 + 0)*256 + lane*4);
            oB += *(f32x4*)(OB + ((size_t)w*2 + 1)*256 + lane*4);
        }
        float lA = __shfl(oA.x, 32 + lm);          // row 8 = sum of trunc(p)
        float lB = __shfl(oB.x, 32 + lm);
        float invA = 1.f / lA, invB = 1.f / lB;
        if (quad < 2) {                            // rows e = quad*4+reg in 0..7
            f32x4 sA = { oA.x*invA, oA.y*invA, oA.z*invA, oA.w*invA };
            f32x4 sB = { oB.x*invB, oB.y*invB, oB.z*invB, oB.w*invB };
            *(f32x4*)(VL + lm*12 + quad*4)        = sA;
            *(f32x4*)(VL + (16 + lm)*12 + quad*4) = sB;
        }
    }
    __syncthreads();

    // Fused epilogue: 32 px x 64 ch over 256 threads (8 ch each).
    const float g  = gamma[0];
    const int   px = tid & 31;
    const int   cg = tid >> 5;                     // 0..7
    const size_t base = (size_t)b*CC*NPIX + (m0 + px);
    float v[EE];
    #pragma unroll
    for (int e = 0; e < EE; ++e) v[e] = VL[px*12 + e];
    #pragma unroll
    for (int i = 0; i < 8; ++i) {
        const int c = cg*8 + i;
        float o = bos[c];
        #pragma unroll
        for (int e = 0; e < EE; ++e) o += Wos[c*9 + e] * v[e];
        out[(size_t)YSZ + base + (size_t)c*NPIX] = o;
        out[base + (size_t)c*NPIX] = g*o + x[base + (size_t)c*NPIX];
    }
    if (blockIdx.x == 0 && tid == 0) out[2*(size_t)YSZ] = g;  // gamma passthrough
}

extern "C" void kernel_launch(void* const* d_in, const int* in_sizes, int n_in,
                              void* d_out, int out_size, void* d_ws, size_t ws_size,
                              hipStream_t stream) {
    const float* x     = (const float*)d_in[0];
    const float* Wk    = (const float*)d_in[1];
    const float* bk    = (const float*)d_in[2];
    const float* Wq    = (const float*)d_in[3];
    const float* bq    = (const float*)d_in[4];
    const float* Wv    = (const float*)d_in[5];
    const float* bv    = (const float*)d_in[6];
    const float* Wo    = (const float*)d_in[7];
    const float* bo    = (const float*)d_in[8];
    const float* gamma = (const float*)d_in[9];
    float* out = (float*)d_out;

    // ws: QT(512KB) | KT(512KB) | VT(1MB bf16, panelized [b][128][16][32];
    // row 8 = ones, rows 9..15 poison -> only discarded C rows) = 2MB
    unsigned short* QT = (unsigned short*)d_ws;
    unsigned short* KT = QT + (size_t)BN*EE;
    unsigned short* VT = KT + (size_t)BN*EE;

    qkv_kernel<<<BN/64, 192, 0, stream>>>(x, Wk, bk, Wq, bq, Wv, bv, QT, KT, VT);
    attn_fused<<<BB*128, 256, 0, stream>>>(QT, KT, VT, x, Wo, bo, gamma, out);
}